// Round 3
// baseline (322.780 us; speedup 1.0000x reference)
//
#include <hip/hip_runtime.h>
#include <stdint.h>

// SNN forward: conv1 -> scan -> pool1(fused) -> pad -> conv2(MFMA) -> scan
// -> pool2(fused) -> pad -> conv3(MFMA) -> scan -> fc(MFMA) -> reduce -> scan.
// Neuron: u=.75u+x; v=.96875v+u; s=(v>=100); v*=(1-s). Spikes u8 in d_ws.
// R9:  FC GEMM on matrix cores (exact 3-way bf16 weight split).
// R11: conv2/conv3 on matrix cores. Binary spikes are exact bf16; weights
// split hi/mid/lo exactly (as FC). pad_bf16 bakes halo zeros + t-1 delay +
// c->innermost transpose into sP[n][H+2][W+2][tau][16c]; conv_mfma then does
// 27 mfma_32x32x16_bf16 per 32-tau position group with B-frags as direct
// coalesced 16B global loads (no LDS, no masks). conv2 pads CIN 8->16 with
// zeros on BOTH A and B (exact). Old conv_t4 was occupancy/latency-bound
// (41.6us @ 15% occupancy); MFMA work for both convs is ~3us total.

#define T 128
#define AI 0.75f
#define AV 0.96875f
#define THETA 100.0f

typedef __attribute__((ext_vector_type(8))) short v8s;    // 8 x bf16 bits
typedef __attribute__((ext_vector_type(16))) float v16f;  // 32x32 acc

__device__ __forceinline__ void neuron_step(float x, float& u, float& v, float& s) {
    u = AI * u + x;
    v = AV * v + u;
    s = (v >= THETA) ? 1.0f : 0.0f;
    v = v * (1.0f - s);
}

// ---------------- conv1 phase A: x[n][o][h][w][t], lanes over t -------------
__global__ __launch_bounds__(256) void conv1_x(
    const float* __restrict__ in, const float* __restrict__ cw,
    float* __restrict__ xout)
{
    int bid = blockIdx.x;                       // 12800
    int tIdx = (bid % 800) * 256 + threadIdx.x; // within [40][40][128]
    int n = bid / 800;
    int t  = tIdx % T;
    int wx = (tIdx / T) % 40;
    int hy = tIdx / (T * 40);

    float val[18];
    #pragma unroll
    for (int c = 0; c < 2; c++)
      #pragma unroll
      for (int dh = -1; dh <= 1; dh++)
        #pragma unroll
        for (int dw = -1; dw <= 1; dw++) {
            int q = c * 9 + (dh + 1) * 3 + (dw + 1);
            int hh = hy + dh, ww = wx + dw;
            bool ok = (hh >= 0) && (hh < 40) && (ww >= 0) && (ww < 40);
            val[q] = ok ? in[(((n * 2 + c) * 40 + hh) * 40 + ww) * T + t] : 0.0f;
        }

    #pragma unroll 1
    for (int o = 0; o < 8; o++) {
        const float* wp = cw + o * 18;          // uniform -> s_load
        float a = 0.f;
        #pragma unroll
        for (int q = 0; q < 18; q++) a += wp[q] * val[q];
        xout[(((n * 8 + o) * 40 + hy) * 40 + wx) * T + t] = a * 20.0f;
    }
}

// ---------------- scan (transposed via LDS): fp32 x rows -> u8 spikes -------
__global__ __launch_bounds__(256) void scan_spike_t(
    const float* __restrict__ x, uint8_t* __restrict__ out)
{
    __shared__ float lds[256 * 20];
    int tid = threadIdx.x;
    size_t r0 = (size_t)blockIdx.x * 256;
    const float* xb = x + r0 * T;

    float u = 0.f, v = 0.f;
    uint32_t ob[32];

    #pragma unroll
    for (int tb = 0; tb < 8; tb++) {
        __syncthreads();
        #pragma unroll
        for (int k = 0; k < 4; k++) {
            int f = tid + k * 256;
            int row = f >> 2, q = f & 3;
            float4 vv = *(const float4*)(xb + (size_t)row * T + tb * 16 + q * 4);
            *(float4*)&lds[row * 20 + q * 4] = vv;
        }
        __syncthreads();
        #pragma unroll
        for (int k = 0; k < 4; k++) {
            float4 xv = *(const float4*)&lds[tid * 20 + k * 4];
            float s0, s1, s2, s3;
            neuron_step(xv.x, u, v, s0); neuron_step(xv.y, u, v, s1);
            neuron_step(xv.z, u, v, s2); neuron_step(xv.w, u, v, s3);
            ob[tb * 4 + k] = (uint32_t)s0 | ((uint32_t)s1 << 8) |
                             ((uint32_t)s2 << 16) | ((uint32_t)s3 << 24);
        }
    }

    uint32_t* op = (uint32_t*)(out + (r0 + tid) * T);
    #pragma unroll
    for (int k = 0; k < 8; k++)
        *(uint4*)&op[k * 4] = make_uint4(ob[k*4], ob[k*4+1], ob[k*4+2], ob[k*4+3]);
}

// ---------------- pool fused: 2x2 sum (u8 adds, no carry) + scan + delay ----
template<int C, int HO, int WO>
__global__ __launch_bounds__(256) void pool_fused(
    const uint8_t* __restrict__ in, const float* __restrict__ pw_ptr,
    uint8_t* __restrict__ out)
{
    __shared__ uint32_t lds[256 * 20];
    int tid = threadIdx.x;
    size_t r0 = (size_t)blockIdx.x * 256;
    float pw = pw_ptr[0];

    float u = 0.f, v = 0.f;
    uint32_t ob[32];
    uint32_t carry = 0;

    #pragma unroll
    for (int tb = 0; tb < 2; tb++) {
        __syncthreads();
        #pragma unroll
        for (int k = 0; k < 4; k++) {
            int f = tid + k * 256;
            int row = f >> 2, q = f & 3;
            int orow = (int)r0 + row;
            int wx = orow % WO;
            int hy = (orow / WO) % HO;
            int c  = (orow / (WO * HO)) % C;
            int nn = orow / (WO * HO * C);
            const uint8_t* p00 = in +
                (((size_t)(nn * C + c) * (2 * HO) + 2 * hy) * (2 * WO) + 2 * wx) * T;
            int off = tb * 64 + q * 16;
            uint4 a = *(const uint4*)(p00 + off);
            uint4 b = *(const uint4*)(p00 + T + off);
            uint4 cc = *(const uint4*)(p00 + 2 * WO * T + off);
            uint4 d = *(const uint4*)(p00 + 2 * WO * T + T + off);
            *(uint4*)&lds[row * 20 + q * 4] =
                make_uint4(a.x + b.x + cc.x + d.x, a.y + b.y + cc.y + d.y,
                           a.z + b.z + cc.z + d.z, a.w + b.w + cc.w + d.w);
        }
        __syncthreads();
        #pragma unroll
        for (int q = 0; q < 4; q++) {
            uint4 w = *(const uint4*)&lds[tid * 20 + q * 4];
            uint32_t words[4] = {w.x, w.y, w.z, w.w};
            #pragma unroll
            for (int j = 0; j < 4; j++) {
                uint32_t cur = words[j];
                uint32_t del = (cur << 8) | carry;   // delay_shift bytes
                carry = cur >> 24;
                float s0, s1, s2, s3;
                neuron_step(pw * (float)(del & 0xffu),         u, v, s0);
                neuron_step(pw * (float)((del >> 8) & 0xffu),  u, v, s1);
                neuron_step(pw * (float)((del >> 16) & 0xffu), u, v, s2);
                neuron_step(pw * (float)((del >> 24) & 0xffu), u, v, s3);
                ob[tb * 16 + q * 4 + j] = (uint32_t)s0 | ((uint32_t)s1 << 8) |
                                          ((uint32_t)s2 << 16) | ((uint32_t)s3 << 24);
            }
        }
    }

    uint32_t* op = (uint32_t*)(out + (r0 + tid) * T);
    #pragma unroll
    for (int k = 0; k < 8; k++)
        *(uint4*)&op[k * 4] = make_uint4(ob[k*4], ob[k*4+1], ob[k*4+2], ob[k*4+3]);
}

// ---------------- pad_bf16: spikes u8 [n][CIN][H][W][T] ->
//                  sP bf16 [n][H+2][W+2][128tau][16c], halo zeros, tau = t-1 -
template<int CIN, int H, int W>
__global__ __launch_bounds__(256) void pad_bf16(
    const uint8_t* __restrict__ s, uint16_t* __restrict__ sP)
{
    int bid = blockIdx.x;                        // 16 * (H+2) * (W+2)
    constexpr int CELLS = (H + 2) * (W + 2);
    int n = bid / CELLS;
    int cell = bid % CELLS;
    int hy = cell / (W + 2) - 1;
    int wx = cell % (W + 2) - 1;
    bool interior = (hy >= 0) && (hy < H) && (wx >= 0) && (wx < W);
    int tid = threadIdx.x;
    int tau = tid >> 1;                          // 0..127
    int g = tid & 1;                             // c-granule (8 c's)
    uint32_t wb[4] = {0u, 0u, 0u, 0u};
    if (interior && tau >= 1) {
        const uint8_t* sp = s + (((size_t)(n * CIN) * H + hy) * W + wx) * T + tau - 1;
        #pragma unroll
        for (int e = 0; e < 8; e++) {
            int c = g * 8 + e;
            uint32_t b = (c < CIN) ? (uint32_t)sp[(size_t)c * H * W * T] : 0u;
            if (b) wb[e >> 1] |= 0x3F80u << ((e & 1) * 16);
        }
    }
    *(uint4*)(sP + (size_t)bid * 2048 + tau * 16 + g * 8) =
        make_uint4(wb[0], wb[1], wb[2], wb[3]);
}

// ---------------- apack_w: conv weights -> MFMA A-frags, 3 exact planes -----
// Layout: apk[conv][plane][delta][lane][8c] bf16; lane: o=lane&31, c0=(lane>>5)*8.
__global__ __launch_bounds__(64) void apack_w(
    const float* __restrict__ c2w, const float* __restrict__ c3w,
    uint16_t* __restrict__ apk)
{
    int bid = blockIdx.x;                        // 54 = 2 conv x 3 plane x 9 d
    int conv = bid / 27;
    int plane = (bid % 27) / 9;
    int dlt = bid % 9;
    int lane = threadIdx.x;
    int o = lane & 31, chi = (lane >> 5) * 8;
    int CO = conv ? 32 : 16;
    int CI = conv ? 16 : 8;
    const float* Wp = conv ? c3w : c2w;
    uint32_t wb[4] = {0u, 0u, 0u, 0u};
    #pragma unroll
    for (int e = 0; e < 8; e++) {
        int c = chi + e;
        float w = (o < CO && c < CI) ? Wp[((size_t)o * CI + c) * 9 + dlt] : 0.f;
        uint32_t b0 = __float_as_uint(w);
        uint16_t hi = (uint16_t)(b0 >> 16);
        float r1 = w - __uint_as_float(b0 & 0xFFFF0000u);     // exact
        uint32_t b1 = __float_as_uint(r1);
        uint16_t md = (uint16_t)(b1 >> 16);
        float r2 = r1 - __uint_as_float(b1 & 0xFFFF0000u);    // exact
        uint16_t lo = (uint16_t)(__float_as_uint(r2) >> 16);  // exact (<=8 bits)
        uint32_t pv = (plane == 0) ? hi : ((plane == 1) ? md : lo);
        wb[e >> 1] |= pv << ((e & 1) * 16);
    }
    *(uint4*)(apk + ((size_t)conv * 27 + plane * 9 + dlt) * 512 + lane * 8) =
        make_uint4(wb[0], wb[1], wb[2], wb[3]);
}

// ---------------- conv_mfma: D[32o][32tau] = sum_{plane,delta} A*B ----------
// One wave per (n,hy,wx,tau-chunk). B-frag = direct coalesced 16B global load
// from sP (halo+delay baked). A-frags double-buffered across the 3 planes.
// Layouts as verified in fc_gemm: A row=lane&31(k=(lane>>5)*8+e),
// B col=lane&31, D col=lane&31, row=(r&3)+8*(r>>2)+4*(lane>>5).
template<int COUT, int H, int W>
__global__ __launch_bounds__(256) void conv_mfma(
    const uint16_t* __restrict__ sP, const uint16_t* __restrict__ apk,
    float scale, float* __restrict__ xout)
{
    int bid = blockIdx.x;                        // 16 * H * W
    int n = bid / (H * W);
    int hw = bid % (H * W);
    int hy = hw / W, wx = hw % W;
    int tid = threadIdx.x;
    int wv = tid >> 6, lane = tid & 63;
    int l31 = lane & 31, lhi = lane >> 5;
    int t0 = wv * 32;

    v8s bfr[9];
    #pragma unroll
    for (int d = 0; d < 9; d++) {
        int dh = d / 3, dw = d % 3;
        const uint16_t* src = sP
            + ((size_t)((n * (H + 2) + hy + dh) * (W + 2) + wx + dw)) * 2048
            + (t0 + l31) * 16 + lhi * 8;
        bfr[d] = *(const v8s*)src;
    }

    const uint16_t* ap = apk + (size_t)lane * 8;
    v8s aA[9], aB[9];
    #pragma unroll
    for (int d = 0; d < 9; d++) aA[d] = *(const v8s*)(ap + d * 512);

    v16f ac0, ac1, ac2;
    #pragma unroll
    for (int e = 0; e < 16; e++) { ac0[e] = 0.f; ac1[e] = 0.f; ac2[e] = 0.f; }

    #pragma unroll
    for (int d = 0; d < 9; d++) aB[d] = *(const v8s*)(ap + (9 + d) * 512);
    #pragma unroll
    for (int d = 0; d < 9; d++)
        ac0 = __builtin_amdgcn_mfma_f32_32x32x16_bf16(aA[d], bfr[d], ac0, 0, 0, 0);
    #pragma unroll
    for (int d = 0; d < 9; d++) aA[d] = *(const v8s*)(ap + (18 + d) * 512);
    #pragma unroll
    for (int d = 0; d < 9; d++)
        ac1 = __builtin_amdgcn_mfma_f32_32x32x16_bf16(aB[d], bfr[d], ac1, 0, 0, 0);
    #pragma unroll
    for (int d = 0; d < 9; d++)
        ac2 = __builtin_amdgcn_mfma_f32_32x32x16_bf16(aA[d], bfr[d], ac2, 0, 0, 0);

    constexpr int NR = (COUT == 32) ? 16 : 8;    // o<COUT rows only
    float* op = xout + ((size_t)(n * COUT) * (H * W) + hw) * 128 + t0 + l31;
    #pragma unroll
    for (int r = 0; r < NR; r++) {
        int o = (r & 3) + 8 * (r >> 2) + 4 * lhi;
        op[(size_t)o * (H * W) * 128] = (ac0[r] + ac1[r] + ac2[r]) * scale;
    }
}

// ---------------- wsplit: fcw[512][3200] -> 3 exact bf16 planes -------------
// w = hi + mid + lo exactly (mantissa truncation 8+8+8 = 24 bits).
__global__ __launch_bounds__(256) void wsplit(
    const float* __restrict__ fw, uint16_t* __restrict__ bs)
{
    int i = blockIdx.x * 256 + threadIdx.x;      // 409,600 threads, 4 elems each
    float4 wv = *(const float4*)(fw + i * 4);
    float w4[4] = {wv.x, wv.y, wv.z, wv.w};
    uint16_t h[4], m[4], l[4];
    #pragma unroll
    for (int j = 0; j < 4; j++) {
        uint32_t b0 = __float_as_uint(w4[j]);
        h[j] = (uint16_t)(b0 >> 16);
        float r1 = w4[j] - __uint_as_float(b0 & 0xFFFF0000u);   // exact
        uint32_t b1 = __float_as_uint(r1);
        m[j] = (uint16_t)(b1 >> 16);
        float r2 = r1 - __uint_as_float(b1 & 0xFFFF0000u);      // exact
        l[j] = (uint16_t)(__float_as_uint(r2) >> 16);           // exact (<=8 bits)
    }
    *(ushort4*)(bs +       0 + i * 4) = make_ushort4(h[0], h[1], h[2], h[3]);
    *(ushort4*)(bs + 1638400 + i * 4) = make_ushort4(m[0], m[1], m[2], m[3]);
    *(ushort4*)(bs + 3276800 + i * 4) = make_ushort4(l[0], l[1], l[2], l[3]);
}

// ---------------- sT: s5 u8 [16][3200][128] -> At bf16 [16][128][3200] ------
// Transpose + delay_shift baked in: At[n][t][c] = s5[n][c][t-1], t=0 -> 0.
__global__ __launch_bounds__(256) void sT_bf16(
    const uint8_t* __restrict__ s5, uint16_t* __restrict__ At)
{
    __shared__ uint8_t tile[64 * 132];           // 64 c-rows x 128 t (+4 pad)
    int bid = blockIdx.x;                        // 800 = 16 n x 50 chunks
    int n = bid / 50;
    int c0 = (bid % 50) * 64;
    int tid = threadIdx.x;
    {
        int row = tid >> 2, q = tid & 3;
        const uint8_t* src = s5 + ((size_t)(n * 3200 + c0 + row)) * T + q * 32;
        *(uint4*)&tile[row * 132 + q * 32]      = *(const uint4*)src;
        *(uint4*)&tile[row * 132 + q * 32 + 16] = *(const uint4*)(src + 16);
    }
    __syncthreads();
    int t = tid >> 1, half = tid & 1;
    uint32_t wb[16];
    if (t == 0) {
        #pragma unroll
        for (int j = 0; j < 16; j++) wb[j] = 0u;
    } else {
        #pragma unroll
        for (int j = 0; j < 16; j++) {
            uint32_t lo = tile[(half * 32 + 2 * j) * 132 + (t - 1)] ? 0x3F80u : 0u;
            uint32_t hi = tile[(half * 32 + 2 * j + 1) * 132 + (t - 1)] ? 0x3F80u : 0u;
            wb[j] = lo | (hi << 16);
        }
    }
    uint16_t* dst = At + ((size_t)(n * 128 + t)) * 3200 + c0 + half * 32;
    #pragma unroll
    for (int k = 0; k < 4; k++)
        *(uint4*)(dst + k * 8) = make_uint4(wb[k*4], wb[k*4+1], wb[k*4+2], wb[k*4+3]);
}

// ---------------- FC GEMM on matrix cores -----------------------------------
#define GLDS16(g, s) __builtin_amdgcn_global_load_lds( \
    (const __attribute__((address_space(1))) uint32_t*)(g), \
    (__attribute__((address_space(3))) uint32_t*)(s), 16, 0, 0)

__global__ __launch_bounds__(128, 2) void fc_gemm_mfma(
    const uint16_t* __restrict__ At,   // [16][128][3200] bf16
    const uint16_t* __restrict__ Bs,   // [3][512][3200] bf16
    float* __restrict__ ypart)         // [10][16][128][512] f32
{
    __shared__ uint8_t lds[65536];     // A [128][64]bf16 @0; B 3x[128][64] @16K
    int bid = blockIdx.x;              // 640 = 10ks x 4ob x 16n (n fastest)
    int n  = bid & 15;
    int ob = (bid >> 4) & 3;
    int ks = bid >> 6;
    int o0 = ob * 128;
    int cbase = ks * 320;

    int tid = threadIdx.x;
    int w = tid >> 6;                  // wave 0/1 -> o-half
    int lane = tid & 63;
    int l31 = lane & 31;
    int lhi = lane >> 5;               // k-half within frag
    int rb = lane >> 3;                // staging: row-in-8
    int gsw = (lane & 7) ^ (rb & 7);   // pre-swizzled source granule

    v16f acc[4][2];
    #pragma unroll
    for (int mi = 0; mi < 4; mi++)
        #pragma unroll
        for (int ni = 0; ni < 2; ni++)
            #pragma unroll
            for (int e = 0; e < 16; e++) acc[mi][ni][e] = 0.0f;

    const uint16_t* Abase = At + (size_t)(n * 128) * 3200 + gsw * 8;

    for (int kc = 0; kc < 5; kc++) {
        int c0 = cbase + kc * 64;
        // ---- stage A: this wave covers rows [w*64, w*64+64) ----
        #pragma unroll
        for (int i = 0; i < 8; i++) {
            int t = w * 64 + i * 8 + rb;
            const uint16_t* src = Abase + (size_t)t * 3200 + c0;
            GLDS16(src, lds + w * 8192 + i * 1024);
        }
        // ---- stage B: this wave covers 24KB of the 48KB ----
        #pragma unroll
        for (int j = 0; j < 24; j++) {
            int f0 = w * 24576 + j * 1024;
            int s = f0 >> 14;                    // split plane
            int r = ((f0 & 16383) >> 7) + rb;    // o-local row
            const uint16_t* src = Bs + (size_t)(s * 512 + o0 + r) * 3200
                                     + c0 + gsw * 8;
            GLDS16(src, lds + 16384 + f0);
        }
        __syncthreads();                         // drains vmcnt before barrier
        // ---- compute: 4 kf x (3 splits x 2 ni x 4 mi) MFMA ----
        #pragma unroll
        for (int kf = 0; kf < 4; kf++) {
            int gc = kf * 2 + lhi;
            v8s av[4];
            #pragma unroll
            for (int mi = 0; mi < 4; mi++) {
                int t = mi * 32 + l31;
                av[mi] = *(const v8s*)(lds + t * 128 + ((gc ^ (t & 7)) << 4));
            }
            #pragma unroll
            for (int s = 0; s < 3; s++) {
                #pragma unroll
                for (int ni = 0; ni < 2; ni++) {
                    int r = w * 64 + ni * 32 + l31;
                    v8s bv = *(const v8s*)(lds + 16384 + s * 16384 + r * 128
                                           + ((gc ^ (r & 7)) << 4));
                    #pragma unroll
                    for (int mi = 0; mi < 4; mi++)
                        acc[mi][ni] = __builtin_amdgcn_mfma_f32_32x32x16_bf16(
                            av[mi], bv, acc[mi][ni], 0, 0, 0);
                }
            }
        }
        __syncthreads();                         // LDS safe before next stage
    }
    // ---- epilogue: C/D layout col=lane&31, row=(r&3)+8*(r>>2)+4*(lane>>5) --
    float* yp = ypart + (size_t)ks * 1048576 + (size_t)n * 65536;
    #pragma unroll
    for (int mi = 0; mi < 4; mi++)
        #pragma unroll
        for (int ni = 0; ni < 2; ni++) {
            int o = o0 + w * 64 + ni * 32 + l31;
            #pragma unroll
            for (int r = 0; r < 16; r++) {
                int trow = mi * 32 + (r & 3) + 8 * (r >> 2) + 4 * lhi;
                yp[trow * 512 + o] = acc[mi][ni][r];
            }
        }
}

// ---------------- FC partial reduce (10 partials, float4) -------------------
__global__ __launch_bounds__(256) void fc_reduce(
    const float4* __restrict__ yp, float4* __restrict__ ys)
{
    int id = blockIdx.x * 256 + threadIdx.x;          // 262,144
    float4 x = yp[id];
    #pragma unroll
    for (int k = 1; k < 10; k++) {
        float4 y = yp[(size_t)k * 262144 + id];
        x.x += y.x; x.y += y.y; x.z += y.z; x.w += y.w;
    }
    ys[id] = x;
}

__global__ __launch_bounds__(64) void fc_scan(
    const float* __restrict__ ysum,   // [16][128][512]
    float* __restrict__ out)          // [16][512][128]
{
    int id = blockIdx.x * 64 + threadIdx.x;           // 8192
    int o = id & 511;
    int n = id >> 9;
    float u = 0.f, v = 0.f;
    float prev = 0.f;                 // final delay_shift
    for (int tb = 0; tb < T / 4; tb++) {
        float b0, b1, b2, b3;
        float x, s;
        x = ysum[(n * T + tb * 4 + 0) * 512 + o]; neuron_step(x, u, v, s); b0 = prev; prev = s;
        x = ysum[(n * T + tb * 4 + 1) * 512 + o]; neuron_step(x, u, v, s); b1 = prev; prev = s;
        x = ysum[(n * T + tb * 4 + 2) * 512 + o]; neuron_step(x, u, v, s); b2 = prev; prev = s;
        x = ysum[(n * T + tb * 4 + 3) * 512 + o]; neuron_step(x, u, v, s); b3 = prev; prev = s;
        *(float4*)&out[((size_t)(n * 512 + o)) * T + tb * 4] = make_float4(b0, b1, b2, b3);
    }
}

// ---------------- launch ----------------------------------------------------
extern "C" void kernel_launch(void* const* d_in, const int* in_sizes, int n_in,
                              void* d_out, int out_size, void* d_ws, size_t ws_size,
                              hipStream_t stream) {
    const float* spike = (const float*)d_in[0];   // [16][2][40][40][128]
    const float* c1w   = (const float*)d_in[1];   // [8][2][3][3]
    const float* c2w   = (const float*)d_in[2];   // [16][8][3][3]
    const float* c3w   = (const float*)d_in[3];   // [32][16][3][3]
    const float* p1w   = (const float*)d_in[4];   // scalar
    const float* p2w   = (const float*)d_in[5];   // scalar
    const float* fcw   = (const float*)d_in[6];   // [512][3200]
    float* out = (float*)d_out;                   // [16][512][128]

    char* ws = (char*)d_ws;
    // Lifetime-ordered map (max 147,511,296 < previously-used 167,116,800):
    float*    xbuf1 = (float*)(ws);               // [0,104,857,600) conv1 x
    uint8_t*  s1    = (uint8_t*)(ws + 104857600); // -> 131,072,000
    uint16_t* Bs16  = (uint16_t*)(ws + 131072000);// -> 140,902,400 (alive->fc)
    uint16_t* Apk   = (uint16_t*)(ws + 140902400);// -> 140,957,696 (alive->conv3)
    uint8_t*  s2    = (uint8_t*)(ws + 140957696); // -> 147,511,296
    uint16_t* s2P   = (uint16_t*)(ws);            // 31,719,424 (xbuf1 dead)
    float*    xbuf  = (float*)(ws + 31719424);    // -> 84,148,224 (conv2/3 x)
    uint8_t*  s3    = (uint8_t*)(ws + 84148224);  // -> 97,255,424
    uint8_t*  s4    = (uint8_t*)(ws + 97255424);  // -> 100,532,224
    uint16_t* s4P   = (uint16_t*)(ws);            // 9,437,184 (s2P dead)
    uint8_t*  s5    = (uint8_t*)(ws + 100532224); // -> 107,085,824
    uint16_t* At16  = (uint16_t*)(ws);            // 13,107,200 (s4P dead)
    float*    ypart = (float*)(ws + 13107200);    // -> 55,050,240
    float*    ysumb = (float*)(ws + 55050240);    // -> 59,244,544

    conv1_x<<<12800, 256, 0, stream>>>(spike, c1w, xbuf1);
    scan_spike_t<<<800, 256, 0, stream>>>(xbuf1, s1);     // xbuf1 dead after
    wsplit<<<1600, 256, 0, stream>>>(fcw, Bs16);
    apack_w<<<54, 64, 0, stream>>>(c2w, c3w, Apk);

    pool_fused<8, 20, 20><<<200, 256, 0, stream>>>(s1, p1w, s2);
    pad_bf16<8, 20, 20><<<16 * 22 * 22, 256, 0, stream>>>(s2, s2P);
    conv_mfma<16, 20, 20><<<16 * 400, 256, 0, stream>>>(s2P, Apk, 100.0f, xbuf);
    scan_spike_t<<<400, 256, 0, stream>>>(xbuf, s3);

    pool_fused<16, 10, 10><<<100, 256, 0, stream>>>(s3, p2w, s4);
    pad_bf16<16, 10, 10><<<16 * 12 * 12, 256, 0, stream>>>(s4, s4P);
    conv_mfma<32, 10, 10><<<16 * 100, 256, 0, stream>>>(s4P, Apk + 13824, 100.0f, xbuf);
    scan_spike_t<<<200, 256, 0, stream>>>(xbuf, s5);

    sT_bf16<<<800, 256, 0, stream>>>(s5, At16);
    fc_gemm_mfma<<<640, 128, 0, stream>>>(At16, Bs16, ypart);
    fc_reduce<<<1024, 256, 0, stream>>>((const float4*)ypart, (float4*)ysumb);
    fc_scan<<<128, 64, 0, stream>>>(ysumb, out);
}

// Round 4
// 296.706 us; speedup vs baseline: 1.0879x; 1.0879x over previous
//
#include <hip/hip_runtime.h>
#include <stdint.h>

// SNN forward: conv1 -> scan -> pool1(fused) -> pad -> conv2+scan(MFMA,fused)
// -> pool2(fused) -> pad -> conv3+scan(MFMA,fused) -> fc(MFMA) -> reduce -> scan.
// Neuron: u=.75u+x; v=.96875v+u; s=(v>=100); v*=(1-s). Spikes u8 in d_ws.
// R9:  FC GEMM on matrix cores (exact 3-way bf16 weight split).
// R11: conv2/conv3 on matrix cores via pre-padded/delayed sP + A-frag weights.
// R12: scan fused INTO the MFMA conv (block holds all 128 t in LDS; 128
// threads scan rows serially, write u8 spikes directly) -- kills the 104 MB
// fp32 xbuf round-trip + 2 scan dispatches. XCD-contiguous block swizzle
// (vbid=(bid&7)*per+bid>>3) fixes the 2.5x sP over-fetch seen in R3
// (FETCH 81 MB vs 31.7 MB tensor: neighbor positions were round-robined
// across XCD L2s). R8's "don't fuse scan into conv" was for the t-parallel
// VALU conv; the MFMA conv holds t in-block by construction.

#define T 128
#define AI 0.75f
#define AV 0.96875f
#define THETA 100.0f

typedef __attribute__((ext_vector_type(8))) short v8s;    // 8 x bf16 bits
typedef __attribute__((ext_vector_type(16))) float v16f;  // 32x32 acc

__device__ __forceinline__ void neuron_step(float x, float& u, float& v, float& s) {
    u = AI * u + x;
    v = AV * v + u;
    s = (v >= THETA) ? 1.0f : 0.0f;
    v = v * (1.0f - s);
}

// ---------------- conv1 phase A: x[n][o][h][w][t], lanes over t -------------
__global__ __launch_bounds__(256) void conv1_x(
    const float* __restrict__ in, const float* __restrict__ cw,
    float* __restrict__ xout)
{
    int bid = blockIdx.x;                       // 12800
    int tIdx = (bid % 800) * 256 + threadIdx.x; // within [40][40][128]
    int n = bid / 800;
    int t  = tIdx % T;
    int wx = (tIdx / T) % 40;
    int hy = tIdx / (T * 40);

    float val[18];
    #pragma unroll
    for (int c = 0; c < 2; c++)
      #pragma unroll
      for (int dh = -1; dh <= 1; dh++)
        #pragma unroll
        for (int dw = -1; dw <= 1; dw++) {
            int q = c * 9 + (dh + 1) * 3 + (dw + 1);
            int hh = hy + dh, ww = wx + dw;
            bool ok = (hh >= 0) && (hh < 40) && (ww >= 0) && (ww < 40);
            val[q] = ok ? in[(((n * 2 + c) * 40 + hh) * 40 + ww) * T + t] : 0.0f;
        }

    #pragma unroll 1
    for (int o = 0; o < 8; o++) {
        const float* wp = cw + o * 18;          // uniform -> s_load
        float a = 0.f;
        #pragma unroll
        for (int q = 0; q < 18; q++) a += wp[q] * val[q];
        xout[(((n * 8 + o) * 40 + hy) * 40 + wx) * T + t] = a * 20.0f;
    }
}

// ---------------- scan (transposed via LDS): fp32 x rows -> u8 spikes -------
__global__ __launch_bounds__(256) void scan_spike_t(
    const float* __restrict__ x, uint8_t* __restrict__ out)
{
    __shared__ float lds[256 * 20];
    int tid = threadIdx.x;
    size_t r0 = (size_t)blockIdx.x * 256;
    const float* xb = x + r0 * T;

    float u = 0.f, v = 0.f;
    uint32_t ob[32];

    #pragma unroll
    for (int tb = 0; tb < 8; tb++) {
        __syncthreads();
        #pragma unroll
        for (int k = 0; k < 4; k++) {
            int f = tid + k * 256;
            int row = f >> 2, q = f & 3;
            float4 vv = *(const float4*)(xb + (size_t)row * T + tb * 16 + q * 4);
            *(float4*)&lds[row * 20 + q * 4] = vv;
        }
        __syncthreads();
        #pragma unroll
        for (int k = 0; k < 4; k++) {
            float4 xv = *(const float4*)&lds[tid * 20 + k * 4];
            float s0, s1, s2, s3;
            neuron_step(xv.x, u, v, s0); neuron_step(xv.y, u, v, s1);
            neuron_step(xv.z, u, v, s2); neuron_step(xv.w, u, v, s3);
            ob[tb * 4 + k] = (uint32_t)s0 | ((uint32_t)s1 << 8) |
                             ((uint32_t)s2 << 16) | ((uint32_t)s3 << 24);
        }
    }

    uint32_t* op = (uint32_t*)(out + (r0 + tid) * T);
    #pragma unroll
    for (int k = 0; k < 8; k++)
        *(uint4*)&op[k * 4] = make_uint4(ob[k*4], ob[k*4+1], ob[k*4+2], ob[k*4+3]);
}

// ---------------- pool fused: 2x2 sum (u8 adds, no carry) + scan + delay ----
template<int C, int HO, int WO>
__global__ __launch_bounds__(256) void pool_fused(
    const uint8_t* __restrict__ in, const float* __restrict__ pw_ptr,
    uint8_t* __restrict__ out)
{
    __shared__ uint32_t lds[256 * 20];
    int tid = threadIdx.x;
    size_t r0 = (size_t)blockIdx.x * 256;
    float pw = pw_ptr[0];

    float u = 0.f, v = 0.f;
    uint32_t ob[32];
    uint32_t carry = 0;

    #pragma unroll
    for (int tb = 0; tb < 2; tb++) {
        __syncthreads();
        #pragma unroll
        for (int k = 0; k < 4; k++) {
            int f = tid + k * 256;
            int row = f >> 2, q = f & 3;
            int orow = (int)r0 + row;
            int wx = orow % WO;
            int hy = (orow / WO) % HO;
            int c  = (orow / (WO * HO)) % C;
            int nn = orow / (WO * HO * C);
            const uint8_t* p00 = in +
                (((size_t)(nn * C + c) * (2 * HO) + 2 * hy) * (2 * WO) + 2 * wx) * T;
            int off = tb * 64 + q * 16;
            uint4 a = *(const uint4*)(p00 + off);
            uint4 b = *(const uint4*)(p00 + T + off);
            uint4 cc = *(const uint4*)(p00 + 2 * WO * T + off);
            uint4 d = *(const uint4*)(p00 + 2 * WO * T + T + off);
            *(uint4*)&lds[row * 20 + q * 4] =
                make_uint4(a.x + b.x + cc.x + d.x, a.y + b.y + cc.y + d.y,
                           a.z + b.z + cc.z + d.z, a.w + b.w + cc.w + d.w);
        }
        __syncthreads();
        #pragma unroll
        for (int q = 0; q < 4; q++) {
            uint4 w = *(const uint4*)&lds[tid * 20 + q * 4];
            uint32_t words[4] = {w.x, w.y, w.z, w.w};
            #pragma unroll
            for (int j = 0; j < 4; j++) {
                uint32_t cur = words[j];
                uint32_t del = (cur << 8) | carry;   // delay_shift bytes
                carry = cur >> 24;
                float s0, s1, s2, s3;
                neuron_step(pw * (float)(del & 0xffu),         u, v, s0);
                neuron_step(pw * (float)((del >> 8) & 0xffu),  u, v, s1);
                neuron_step(pw * (float)((del >> 16) & 0xffu), u, v, s2);
                neuron_step(pw * (float)((del >> 24) & 0xffu), u, v, s3);
                ob[tb * 16 + q * 4 + j] = (uint32_t)s0 | ((uint32_t)s1 << 8) |
                                          ((uint32_t)s2 << 16) | ((uint32_t)s3 << 24);
            }
        }
    }

    uint32_t* op = (uint32_t*)(out + (r0 + tid) * T);
    #pragma unroll
    for (int k = 0; k < 8; k++)
        *(uint4*)&op[k * 4] = make_uint4(ob[k*4], ob[k*4+1], ob[k*4+2], ob[k*4+3]);
}

// ---------------- pad_bf16: spikes u8 [n][CIN][H][W][T] ->
//                  sP bf16 [n][H+2][W+2][128tau][16c], halo zeros, tau = t-1 -
template<int CIN, int H, int W>
__global__ __launch_bounds__(256) void pad_bf16(
    const uint8_t* __restrict__ s, uint16_t* __restrict__ sP)
{
    int bid = blockIdx.x;                        // 16 * (H+2) * (W+2)
    constexpr int CELLS = (H + 2) * (W + 2);
    int n = bid / CELLS;
    int cell = bid % CELLS;
    int hy = cell / (W + 2) - 1;
    int wx = cell % (W + 2) - 1;
    bool interior = (hy >= 0) && (hy < H) && (wx >= 0) && (wx < W);
    int tid = threadIdx.x;
    int tau = tid >> 1;                          // 0..127
    int g = tid & 1;                             // c-granule (8 c's)
    uint32_t wb[4] = {0u, 0u, 0u, 0u};
    if (interior && tau >= 1) {
        const uint8_t* sp = s + (((size_t)(n * CIN) * H + hy) * W + wx) * T + tau - 1;
        #pragma unroll
        for (int e = 0; e < 8; e++) {
            int c = g * 8 + e;
            uint32_t b = (c < CIN) ? (uint32_t)sp[(size_t)c * H * W * T] : 0u;
            if (b) wb[e >> 1] |= 0x3F80u << ((e & 1) * 16);
        }
    }
    *(uint4*)(sP + (size_t)bid * 2048 + tau * 16 + g * 8) =
        make_uint4(wb[0], wb[1], wb[2], wb[3]);
}

// ---------------- apack_w: conv weights -> MFMA A-frags, 3 exact planes -----
// Layout: apk[conv][plane][delta][lane][8c] bf16; lane: o=lane&31, c0=(lane>>5)*8.
__global__ __launch_bounds__(64) void apack_w(
    const float* __restrict__ c2w, const float* __restrict__ c3w,
    uint16_t* __restrict__ apk)
{
    int bid = blockIdx.x;                        // 54 = 2 conv x 3 plane x 9 d
    int conv = bid / 27;
    int plane = (bid % 27) / 9;
    int dlt = bid % 9;
    int lane = threadIdx.x;
    int o = lane & 31, chi = (lane >> 5) * 8;
    int CO = conv ? 32 : 16;
    int CI = conv ? 16 : 8;
    const float* Wp = conv ? c3w : c2w;
    uint32_t wb[4] = {0u, 0u, 0u, 0u};
    #pragma unroll
    for (int e = 0; e < 8; e++) {
        int c = chi + e;
        float w = (o < CO && c < CI) ? Wp[((size_t)o * CI + c) * 9 + dlt] : 0.f;
        uint32_t b0 = __float_as_uint(w);
        uint16_t hi = (uint16_t)(b0 >> 16);
        float r1 = w - __uint_as_float(b0 & 0xFFFF0000u);     // exact
        uint32_t b1 = __float_as_uint(r1);
        uint16_t md = (uint16_t)(b1 >> 16);
        float r2 = r1 - __uint_as_float(b1 & 0xFFFF0000u);    // exact
        uint16_t lo = (uint16_t)(__float_as_uint(r2) >> 16);  // exact (<=8 bits)
        uint32_t pv = (plane == 0) ? hi : ((plane == 1) ? md : lo);
        wb[e >> 1] |= pv << ((e & 1) * 16);
    }
    *(uint4*)(apk + ((size_t)conv * 27 + plane * 9 + dlt) * 512 + lane * 8) =
        make_uint4(wb[0], wb[1], wb[2], wb[3]);
}

// ---------------- conv_scan_mfma: MFMA conv + in-block LIF scan -------------
// Block = 256 thr (4 waves = 4 tau-chunks) x PB positions, all COUT, all T.
// Phase 1: wave wv computes D[32o][32tau] per position (27 mfma_32x32x16),
// stores x=D*scale to LDS [128 rows][130] f32 (stride 130: 2-way-free banks).
// Phase 2: 128 threads scan one row each over t=0..127, write u8 spikes.
// XCD-contiguous vbid swizzle keeps each XCD's sP working set in its L2.
// Layouts as verified in fc_gemm: A k=(lane>>5)*8+e, B col=lane&31,
// D col=lane&31(tau), row o=(r&3)+8*(r>>2)+4*(lane>>5).
template<int COUT, int PB, int H, int W>
__global__ __launch_bounds__(256, 2) void conv_scan_mfma(
    const uint16_t* __restrict__ sP, const uint16_t* __restrict__ apk,
    float scale, uint8_t* __restrict__ sout)
{
    __shared__ float ldsF[128 * 130];            // 66,560 B
    constexpr int HW = H * W;
    constexpr int GP = HW / PB;
    int per = (16 * GP) >> 3;                    // blocks per XCD
    int vbid = (blockIdx.x & 7) * per + (blockIdx.x >> 3);
    int n = vbid / GP, grp = vbid % GP;
    int tid = threadIdx.x;
    int wv = tid >> 6, lane = tid & 63;
    int l31 = lane & 31, lhi = lane >> 5;
    int t0 = wv * 32;

    const uint16_t* ap = apk + (size_t)lane * 8;
    v8s a0[9], a1[9], a2[9];
    #pragma unroll
    for (int d = 0; d < 9; d++) {
        a0[d] = *(const v8s*)(ap + d * 512);
        a1[d] = *(const v8s*)(ap + (9 + d) * 512);
        a2[d] = *(const v8s*)(ap + (18 + d) * 512);
    }

    #pragma unroll
    for (int p = 0; p < PB; p++) {
        int hw = grp * PB + p;
        int hy = hw / W, wx = hw % W;
        v8s bfr[9];
        #pragma unroll
        for (int d = 0; d < 9; d++) {
            int dh = d / 3, dw = d % 3;
            const uint16_t* src = sP
                + ((size_t)((n * (H + 2) + hy + dh) * (W + 2) + wx + dw)) * 2048
                + (t0 + l31) * 16 + lhi * 8;
            bfr[d] = *(const v8s*)src;
        }
        v16f ac0, ac1, ac2;
        #pragma unroll
        for (int e = 0; e < 16; e++) { ac0[e] = 0.f; ac1[e] = 0.f; ac2[e] = 0.f; }
        #pragma unroll
        for (int d = 0; d < 9; d++) {
            ac0 = __builtin_amdgcn_mfma_f32_32x32x16_bf16(a0[d], bfr[d], ac0, 0, 0, 0);
            ac1 = __builtin_amdgcn_mfma_f32_32x32x16_bf16(a1[d], bfr[d], ac1, 0, 0, 0);
            ac2 = __builtin_amdgcn_mfma_f32_32x32x16_bf16(a2[d], bfr[d], ac2, 0, 0, 0);
        }
        constexpr int NR = (COUT == 32) ? 16 : 8;
        #pragma unroll
        for (int r = 0; r < NR; r++) {
            int o = (r & 3) + 8 * (r >> 2) + 4 * lhi;
            ldsF[(o * PB + p) * 130 + t0 + l31] =
                (ac0[r] + ac1[r] + ac2[r]) * scale;
        }
    }
    __syncthreads();
    if (tid < 128) {
        int o = tid / PB, p = tid % PB;
        int hw = grp * PB + p;
        float u = 0.f, v = 0.f;
        uint32_t ob[32];
        const float* xr = &ldsF[tid * 130];
        #pragma unroll
        for (int tb = 0; tb < 32; tb++) {
            float2 xa = *(const float2*)(xr + tb * 4);
            float2 xb = *(const float2*)(xr + tb * 4 + 2);
            float s0, s1, s2, s3;
            neuron_step(xa.x, u, v, s0); neuron_step(xa.y, u, v, s1);
            neuron_step(xb.x, u, v, s2); neuron_step(xb.y, u, v, s3);
            ob[tb] = (uint32_t)s0 | ((uint32_t)s1 << 8) |
                     ((uint32_t)s2 << 16) | ((uint32_t)s3 << 24);
        }
        uint32_t* op = (uint32_t*)(sout + ((size_t)(n * COUT + o) * HW + hw) * 128);
        #pragma unroll
        for (int k = 0; k < 8; k++)
            *(uint4*)&op[k * 4] =
                make_uint4(ob[k*4], ob[k*4+1], ob[k*4+2], ob[k*4+3]);
    }
}

// ---------------- wsplit: fcw[512][3200] -> 3 exact bf16 planes -------------
// w = hi + mid + lo exactly (mantissa truncation 8+8+8 = 24 bits).
__global__ __launch_bounds__(256) void wsplit(
    const float* __restrict__ fw, uint16_t* __restrict__ bs)
{
    int i = blockIdx.x * 256 + threadIdx.x;      // 409,600 threads, 4 elems each
    float4 wv = *(const float4*)(fw + i * 4);
    float w4[4] = {wv.x, wv.y, wv.z, wv.w};
    uint16_t h[4], m[4], l[4];
    #pragma unroll
    for (int j = 0; j < 4; j++) {
        uint32_t b0 = __float_as_uint(w4[j]);
        h[j] = (uint16_t)(b0 >> 16);
        float r1 = w4[j] - __uint_as_float(b0 & 0xFFFF0000u);   // exact
        uint32_t b1 = __float_as_uint(r1);
        m[j] = (uint16_t)(b1 >> 16);
        float r2 = r1 - __uint_as_float(b1 & 0xFFFF0000u);      // exact
        l[j] = (uint16_t)(__float_as_uint(r2) >> 16);           // exact (<=8 bits)
    }
    *(ushort4*)(bs +       0 + i * 4) = make_ushort4(h[0], h[1], h[2], h[3]);
    *(ushort4*)(bs + 1638400 + i * 4) = make_ushort4(m[0], m[1], m[2], m[3]);
    *(ushort4*)(bs + 3276800 + i * 4) = make_ushort4(l[0], l[1], l[2], l[3]);
}

// ---------------- sT: s5 u8 [16][3200][128] -> At bf16 [16][128][3200] ------
// Transpose + delay_shift baked in: At[n][t][c] = s5[n][c][t-1], t=0 -> 0.
__global__ __launch_bounds__(256) void sT_bf16(
    const uint8_t* __restrict__ s5, uint16_t* __restrict__ At)
{
    __shared__ uint8_t tile[64 * 132];           // 64 c-rows x 128 t (+4 pad)
    int bid = blockIdx.x;                        // 800 = 16 n x 50 chunks
    int n = bid / 50;
    int c0 = (bid % 50) * 64;
    int tid = threadIdx.x;
    {
        int row = tid >> 2, q = tid & 3;
        const uint8_t* src = s5 + ((size_t)(n * 3200 + c0 + row)) * T + q * 32;
        *(uint4*)&tile[row * 132 + q * 32]      = *(const uint4*)src;
        *(uint4*)&tile[row * 132 + q * 32 + 16] = *(const uint4*)(src + 16);
    }
    __syncthreads();
    int t = tid >> 1, half = tid & 1;
    uint32_t wb[16];
    if (t == 0) {
        #pragma unroll
        for (int j = 0; j < 16; j++) wb[j] = 0u;
    } else {
        #pragma unroll
        for (int j = 0; j < 16; j++) {
            uint32_t lo = tile[(half * 32 + 2 * j) * 132 + (t - 1)] ? 0x3F80u : 0u;
            uint32_t hi = tile[(half * 32 + 2 * j + 1) * 132 + (t - 1)] ? 0x3F80u : 0u;
            wb[j] = lo | (hi << 16);
        }
    }
    uint16_t* dst = At + ((size_t)(n * 128 + t)) * 3200 + c0 + half * 32;
    #pragma unroll
    for (int k = 0; k < 4; k++)
        *(uint4*)(dst + k * 8) = make_uint4(wb[k*4], wb[k*4+1], wb[k*4+2], wb[k*4+3]);
}

// ---------------- FC GEMM on matrix cores -----------------------------------
#define GLDS16(g, s) __builtin_amdgcn_global_load_lds( \
    (const __attribute__((address_space(1))) uint32_t*)(g), \
    (__attribute__((address_space(3))) uint32_t*)(s), 16, 0, 0)

__global__ __launch_bounds__(128, 2) void fc_gemm_mfma(
    const uint16_t* __restrict__ At,   // [16][128][3200] bf16
    const uint16_t* __restrict__ Bs,   // [3][512][3200] bf16
    float* __restrict__ ypart)         // [10][16][128][512] f32
{
    __shared__ uint8_t lds[65536];     // A [128][64]bf16 @0; B 3x[128][64] @16K
    int bid = blockIdx.x;              // 640 = 10ks x 4ob x 16n (n fastest)
    int n  = bid & 15;
    int ob = (bid >> 4) & 3;
    int ks = bid >> 6;
    int o0 = ob * 128;
    int cbase = ks * 320;

    int tid = threadIdx.x;
    int w = tid >> 6;                  // wave 0/1 -> o-half
    int lane = tid & 63;
    int l31 = lane & 31;
    int lhi = lane >> 5;               // k-half within frag
    int rb = lane >> 3;                // staging: row-in-8
    int gsw = (lane & 7) ^ (rb & 7);   // pre-swizzled source granule

    v16f acc[4][2];
    #pragma unroll
    for (int mi = 0; mi < 4; mi++)
        #pragma unroll
        for (int ni = 0; ni < 2; ni++)
            #pragma unroll
            for (int e = 0; e < 16; e++) acc[mi][ni][e] = 0.0f;

    const uint16_t* Abase = At + (size_t)(n * 128) * 3200 + gsw * 8;

    for (int kc = 0; kc < 5; kc++) {
        int c0 = cbase + kc * 64;
        // ---- stage A: this wave covers rows [w*64, w*64+64) ----
        #pragma unroll
        for (int i = 0; i < 8; i++) {
            int t = w * 64 + i * 8 + rb;
            const uint16_t* src = Abase + (size_t)t * 3200 + c0;
            GLDS16(src, lds + w * 8192 + i * 1024);
        }
        // ---- stage B: this wave covers 24KB of the 48KB ----
        #pragma unroll
        for (int j = 0; j < 24; j++) {
            int f0 = w * 24576 + j * 1024;
            int s = f0 >> 14;                    // split plane
            int r = ((f0 & 16383) >> 7) + rb;    // o-local row
            const uint16_t* src = Bs + (size_t)(s * 512 + o0 + r) * 3200
                                     + c0 + gsw * 8;
            GLDS16(src, lds + 16384 + f0);
        }
        __syncthreads();                         // drains vmcnt before barrier
        // ---- compute: 4 kf x (3 splits x 2 ni x 4 mi) MFMA ----
        #pragma unroll
        for (int kf = 0; kf < 4; kf++) {
            int gc = kf * 2 + lhi;
            v8s av[4];
            #pragma unroll
            for (int mi = 0; mi < 4; mi++) {
                int t = mi * 32 + l31;
                av[mi] = *(const v8s*)(lds + t * 128 + ((gc ^ (t & 7)) << 4));
            }
            #pragma unroll
            for (int s = 0; s < 3; s++) {
                #pragma unroll
                for (int ni = 0; ni < 2; ni++) {
                    int r = w * 64 + ni * 32 + l31;
                    v8s bv = *(const v8s*)(lds + 16384 + s * 16384 + r * 128
                                           + ((gc ^ (r & 7)) << 4));
                    #pragma unroll
                    for (int mi = 0; mi < 4; mi++)
                        acc[mi][ni] = __builtin_amdgcn_mfma_f32_32x32x16_bf16(
                            av[mi], bv, acc[mi][ni], 0, 0, 0);
                }
            }
        }
        __syncthreads();                         // LDS safe before next stage
    }
    // ---- epilogue: C/D layout col=lane&31, row=(r&3)+8*(r>>2)+4*(lane>>5) --
    float* yp = ypart + (size_t)ks * 1048576 + (size_t)n * 65536;
    #pragma unroll
    for (int mi = 0; mi < 4; mi++)
        #pragma unroll
        for (int ni = 0; ni < 2; ni++) {
            int o = o0 + w * 64 + ni * 32 + l31;
            #pragma unroll
            for (int r = 0; r < 16; r++) {
                int trow = mi * 32 + (r & 3) + 8 * (r >> 2) + 4 * lhi;
                yp[trow * 512 + o] = acc[mi][ni][r];
            }
        }
}

// ---------------- FC partial reduce (10 partials, float4) -------------------
__global__ __launch_bounds__(256) void fc_reduce(
    const float4* __restrict__ yp, float4* __restrict__ ys)
{
    int id = blockIdx.x * 256 + threadIdx.x;          // 262,144
    float4 x = yp[id];
    #pragma unroll
    for (int k = 1; k < 10; k++) {
        float4 y = yp[(size_t)k * 262144 + id];
        x.x += y.x; x.y += y.y; x.z += y.z; x.w += y.w;
    }
    ys[id] = x;
}

__global__ __launch_bounds__(64) void fc_scan(
    const float* __restrict__ ysum,   // [16][128][512]
    float* __restrict__ out)          // [16][512][128]
{
    int id = blockIdx.x * 64 + threadIdx.x;           // 8192
    int o = id & 511;
    int n = id >> 9;
    float u = 0.f, v = 0.f;
    float prev = 0.f;                 // final delay_shift
    for (int tb = 0; tb < T / 4; tb++) {
        float b0, b1, b2, b3;
        float x, s;
        x = ysum[(n * T + tb * 4 + 0) * 512 + o]; neuron_step(x, u, v, s); b0 = prev; prev = s;
        x = ysum[(n * T + tb * 4 + 1) * 512 + o]; neuron_step(x, u, v, s); b1 = prev; prev = s;
        x = ysum[(n * T + tb * 4 + 2) * 512 + o]; neuron_step(x, u, v, s); b2 = prev; prev = s;
        x = ysum[(n * T + tb * 4 + 3) * 512 + o]; neuron_step(x, u, v, s); b3 = prev; prev = s;
        *(float4*)&out[((size_t)(n * 512 + o)) * T + tb * 4] = make_float4(b0, b1, b2, b3);
    }
}

// ---------------- launch ----------------------------------------------------
extern "C" void kernel_launch(void* const* d_in, const int* in_sizes, int n_in,
                              void* d_out, int out_size, void* d_ws, size_t ws_size,
                              hipStream_t stream) {
    const float* spike = (const float*)d_in[0];   // [16][2][40][40][128]
    const float* c1w   = (const float*)d_in[1];   // [8][2][3][3]
    const float* c2w   = (const float*)d_in[2];   // [16][8][3][3]
    const float* c3w   = (const float*)d_in[3];   // [32][16][3][3]
    const float* p1w   = (const float*)d_in[4];   // scalar
    const float* p2w   = (const float*)d_in[5];   // scalar
    const float* fcw   = (const float*)d_in[6];   // [512][3200]
    float* out = (float*)d_out;                   // [16][512][128]

    char* ws = (char*)d_ws;
    // Lifetime-ordered map:
    float*    xbuf1 = (float*)(ws);               // [0,104,857,600) conv1 x
    uint8_t*  s1    = (uint8_t*)(ws + 104857600); // -> 131,072,000
    uint16_t* Bs16  = (uint16_t*)(ws + 131072000);// -> 140,902,400 (alive->fc)
    uint16_t* Apk   = (uint16_t*)(ws + 140902400);// -> 140,957,696 (alive->conv3)
    uint8_t*  s2    = (uint8_t*)(ws + 140957696); // -> 147,511,296
    uint16_t* s2P   = (uint16_t*)(ws);            // 31,719,424 (xbuf1 dead)
    uint8_t*  s3    = (uint8_t*)(ws + 84148224);  // -> 97,255,424
    uint8_t*  s4    = (uint8_t*)(ws + 97255424);  // -> 100,532,224
    uint16_t* s4P   = (uint16_t*)(ws);            // 9,437,184 (s2P dead)
    uint8_t*  s5    = (uint8_t*)(ws + 100532224); // -> 107,085,824
    uint16_t* At16  = (uint16_t*)(ws);            // 13,107,200 (s4P dead)
    float*    ypart = (float*)(ws + 13107200);    // -> 55,050,240
    float*    ysumb = (float*)(ws + 55050240);    // -> 59,244,544

    conv1_x<<<12800, 256, 0, stream>>>(spike, c1w, xbuf1);
    scan_spike_t<<<800, 256, 0, stream>>>(xbuf1, s1);     // xbuf1 dead after
    wsplit<<<1600, 256, 0, stream>>>(fcw, Bs16);
    apack_w<<<54, 64, 0, stream>>>(c2w, c3w, Apk);

    pool_fused<8, 20, 20><<<200, 256, 0, stream>>>(s1, p1w, s2);
    pad_bf16<8, 20, 20><<<16 * 22 * 22, 256, 0, stream>>>(s2, s2P);
    conv_scan_mfma<16, 8, 20, 20><<<800, 256, 0, stream>>>(s2P, Apk, 100.0f, s3);

    pool_fused<16, 10, 10><<<100, 256, 0, stream>>>(s3, p2w, s4);
    pad_bf16<16, 10, 10><<<16 * 12 * 12, 256, 0, stream>>>(s4, s4P);
    conv_scan_mfma<32, 4, 10, 10><<<400, 256, 0, stream>>>(s4P, Apk + 13824, 100.0f, s5);

    sT_bf16<<<800, 256, 0, stream>>>(s5, At16);
    fc_gemm_mfma<<<640, 128, 0, stream>>>(At16, Bs16, ypart);
    fc_reduce<<<1024, 256, 0, stream>>>((const float4*)ypart, (float4*)ysumb);
    fc_scan<<<128, 64, 0, stream>>>(ysumb, out);
}

// Round 5
// 255.841 us; speedup vs baseline: 1.2616x; 1.1597x over previous
//
#include <hip/hip_runtime.h>
#include <stdint.h>

// SNN forward: conv1+scan(fused VALU) -> pool1(fused) -> pad -> conv2+scan
// (MFMA,fused) -> pool2(fused) -> pad -> conv3+scan(MFMA,fused) -> fc(MFMA)
// -> reduce -> scan.
// Neuron: u=.75u+x; v=.96875v+u; s=(v>=100); v*=(1-s). Spikes u8 in d_ws.
// R9:  FC GEMM on matrix cores (exact 3-way bf16 weight split).
// R11: conv2/conv3 on matrix cores via pre-padded/delayed sP + A-frag weights.
// R12: scan fused INTO the MFMA convs; XCD-contiguous block swizzle.
// R13: (a) conv1+scan fused the same way (VALU conv: CIN=2 makes MFMA
// padding wasteful) -- deletes the 104MB fp32 xbuf round-trip + scan
// dispatch (was 58us combined, 156MB traffic). FMA order kept bitwise
// identical to old conv1_x. (b) fc_gemm rebuilt as 4-wave/256-thr blocks
// (2x2 wave split over t/o halves): R4 counters showed 6.5% occupancy =
// 1 wave/SIMD (128-thr blocks + 64KB LDS) -- staging drain had nothing to
// overlap with. Same tile/LDS/swizzle/accumulation order, occupancy 2x.

#define T 128
#define AI 0.75f
#define AV 0.96875f
#define THETA 100.0f

typedef __attribute__((ext_vector_type(8))) short v8s;    // 8 x bf16 bits
typedef __attribute__((ext_vector_type(16))) float v16f;  // 32x32 acc

__device__ __forceinline__ void neuron_step(float x, float& u, float& v, float& s) {
    u = AI * u + x;
    v = AV * v + u;
    s = (v >= THETA) ? 1.0f : 0.0f;
    v = v * (1.0f - s);
}

// ---------------- conv1 + scan fused: spikes fp32 -> s1 u8 ------------------
// Block = (n, hy, 8-wx group); 256 thr = 8 wx x 32 t-threads.
// Phase 1: x[o][wx][t] -> LDS (FMA order identical to old conv1_x).
// Phase 2: 64 threads scan one (o,wx) row each over t, write u8 spikes.
__global__ __launch_bounds__(256) void conv1_scan(
    const float* __restrict__ in, const float* __restrict__ cw,
    uint8_t* __restrict__ sout)
{
    __shared__ float ldsF[64 * 130];             // 33,280 B
    int bid = blockIdx.x;                        // 3200 = 16n x 40hy x 5wg
    int wg = bid % 5;
    int hy = (bid / 5) % 40;
    int n  = bid / 200;
    int tid = threadIdx.x;
    int wxl = tid >> 5, tt = tid & 31, t0 = tt * 4;
    int wx = wg * 8 + wxl;

    float4 tap[18];
    #pragma unroll
    for (int c = 0; c < 2; c++)
      #pragma unroll
      for (int dh = 0; dh < 3; dh++)
        #pragma unroll
        for (int dw = 0; dw < 3; dw++) {
            int q = c * 9 + dh * 3 + dw;
            int hh = hy + dh - 1, ww = wx + dw - 1;
            bool ok = (hh >= 0) && (hh < 40) && (ww >= 0) && (ww < 40);
            tap[q] = ok ? *(const float4*)(in +
                (((size_t)(n * 2 + c) * 40 + hh) * 40 + ww) * T + t0)
                        : make_float4(0.f, 0.f, 0.f, 0.f);
        }

    #pragma unroll
    for (int o = 0; o < 8; o++) {
        const float* wp = cw + o * 18;           // uniform -> s_load
        float a0 = 0.f, a1 = 0.f, a2 = 0.f, a3 = 0.f;
        #pragma unroll
        for (int q = 0; q < 18; q++) {
            a0 += wp[q] * tap[q].x;  a1 += wp[q] * tap[q].y;
            a2 += wp[q] * tap[q].z;  a3 += wp[q] * tap[q].w;
        }
        float* xr = &ldsF[(o * 8 + wxl) * 130 + t0];
        xr[0] = a0 * 20.0f; xr[1] = a1 * 20.0f;
        xr[2] = a2 * 20.0f; xr[3] = a3 * 20.0f;
    }
    __syncthreads();
    if (tid < 64) {
        int o = tid >> 3, wxl2 = tid & 7;
        float u = 0.f, v = 0.f;
        uint32_t ob[32];
        const float* xr = &ldsF[tid * 130];
        #pragma unroll
        for (int tb = 0; tb < 32; tb++) {
            float s0, s1, s2, s3;
            neuron_step(xr[tb * 4 + 0], u, v, s0);
            neuron_step(xr[tb * 4 + 1], u, v, s1);
            neuron_step(xr[tb * 4 + 2], u, v, s2);
            neuron_step(xr[tb * 4 + 3], u, v, s3);
            ob[tb] = (uint32_t)s0 | ((uint32_t)s1 << 8) |
                     ((uint32_t)s2 << 16) | ((uint32_t)s3 << 24);
        }
        uint32_t* op = (uint32_t*)(sout +
            (((size_t)(n * 8 + o) * 40 + hy) * 40 + wg * 8 + wxl2) * T);
        #pragma unroll
        for (int k = 0; k < 8; k++)
            *(uint4*)&op[k * 4] =
                make_uint4(ob[k*4], ob[k*4+1], ob[k*4+2], ob[k*4+3]);
    }
}

// ---------------- pool fused: 2x2 sum (u8 adds, no carry) + scan + delay ----
template<int C, int HO, int WO>
__global__ __launch_bounds__(256) void pool_fused(
    const uint8_t* __restrict__ in, const float* __restrict__ pw_ptr,
    uint8_t* __restrict__ out)
{
    __shared__ uint32_t lds[256 * 20];
    int tid = threadIdx.x;
    size_t r0 = (size_t)blockIdx.x * 256;
    float pw = pw_ptr[0];

    float u = 0.f, v = 0.f;
    uint32_t ob[32];
    uint32_t carry = 0;

    #pragma unroll
    for (int tb = 0; tb < 2; tb++) {
        __syncthreads();
        #pragma unroll
        for (int k = 0; k < 4; k++) {
            int f = tid + k * 256;
            int row = f >> 2, q = f & 3;
            int orow = (int)r0 + row;
            int wx = orow % WO;
            int hy = (orow / WO) % HO;
            int c  = (orow / (WO * HO)) % C;
            int nn = orow / (WO * HO * C);
            const uint8_t* p00 = in +
                (((size_t)(nn * C + c) * (2 * HO) + 2 * hy) * (2 * WO) + 2 * wx) * T;
            int off = tb * 64 + q * 16;
            uint4 a = *(const uint4*)(p00 + off);
            uint4 b = *(const uint4*)(p00 + T + off);
            uint4 cc = *(const uint4*)(p00 + 2 * WO * T + off);
            uint4 d = *(const uint4*)(p00 + 2 * WO * T + T + off);
            *(uint4*)&lds[row * 20 + q * 4] =
                make_uint4(a.x + b.x + cc.x + d.x, a.y + b.y + cc.y + d.y,
                           a.z + b.z + cc.z + d.z, a.w + b.w + cc.w + d.w);
        }
        __syncthreads();
        #pragma unroll
        for (int q = 0; q < 4; q++) {
            uint4 w = *(const uint4*)&lds[tid * 20 + q * 4];
            uint32_t words[4] = {w.x, w.y, w.z, w.w};
            #pragma unroll
            for (int j = 0; j < 4; j++) {
                uint32_t cur = words[j];
                uint32_t del = (cur << 8) | carry;   // delay_shift bytes
                carry = cur >> 24;
                float s0, s1, s2, s3;
                neuron_step(pw * (float)(del & 0xffu),         u, v, s0);
                neuron_step(pw * (float)((del >> 8) & 0xffu),  u, v, s1);
                neuron_step(pw * (float)((del >> 16) & 0xffu), u, v, s2);
                neuron_step(pw * (float)((del >> 24) & 0xffu), u, v, s3);
                ob[tb * 16 + q * 4 + j] = (uint32_t)s0 | ((uint32_t)s1 << 8) |
                                          ((uint32_t)s2 << 16) | ((uint32_t)s3 << 24);
            }
        }
    }

    uint32_t* op = (uint32_t*)(out + (r0 + tid) * T);
    #pragma unroll
    for (int k = 0; k < 8; k++)
        *(uint4*)&op[k * 4] = make_uint4(ob[k*4], ob[k*4+1], ob[k*4+2], ob[k*4+3]);
}

// ---------------- pad_bf16: spikes u8 [n][CIN][H][W][T] ->
//                  sP bf16 [n][H+2][W+2][128tau][16c], halo zeros, tau = t-1 -
template<int CIN, int H, int W>
__global__ __launch_bounds__(256) void pad_bf16(
    const uint8_t* __restrict__ s, uint16_t* __restrict__ sP)
{
    int bid = blockIdx.x;                        // 16 * (H+2) * (W+2)
    constexpr int CELLS = (H + 2) * (W + 2);
    int n = bid / CELLS;
    int cell = bid % CELLS;
    int hy = cell / (W + 2) - 1;
    int wx = cell % (W + 2) - 1;
    bool interior = (hy >= 0) && (hy < H) && (wx >= 0) && (wx < W);
    int tid = threadIdx.x;
    int tau = tid >> 1;                          // 0..127
    int g = tid & 1;                             // c-granule (8 c's)
    uint32_t wb[4] = {0u, 0u, 0u, 0u};
    if (interior && tau >= 1) {
        const uint8_t* sp = s + (((size_t)(n * CIN) * H + hy) * W + wx) * T + tau - 1;
        #pragma unroll
        for (int e = 0; e < 8; e++) {
            int c = g * 8 + e;
            uint32_t b = (c < CIN) ? (uint32_t)sp[(size_t)c * H * W * T] : 0u;
            if (b) wb[e >> 1] |= 0x3F80u << ((e & 1) * 16);
        }
    }
    *(uint4*)(sP + (size_t)bid * 2048 + tau * 16 + g * 8) =
        make_uint4(wb[0], wb[1], wb[2], wb[3]);
}

// ---------------- apack_w: conv weights -> MFMA A-frags, 3 exact planes -----
// Layout: apk[conv][plane][delta][lane][8c] bf16; lane: o=lane&31, c0=(lane>>5)*8.
__global__ __launch_bounds__(64) void apack_w(
    const float* __restrict__ c2w, const float* __restrict__ c3w,
    uint16_t* __restrict__ apk)
{
    int bid = blockIdx.x;                        // 54 = 2 conv x 3 plane x 9 d
    int conv = bid / 27;
    int plane = (bid % 27) / 9;
    int dlt = bid % 9;
    int lane = threadIdx.x;
    int o = lane & 31, chi = (lane >> 5) * 8;
    int CO = conv ? 32 : 16;
    int CI = conv ? 16 : 8;
    const float* Wp = conv ? c3w : c2w;
    uint32_t wb[4] = {0u, 0u, 0u, 0u};
    #pragma unroll
    for (int e = 0; e < 8; e++) {
        int c = chi + e;
        float w = (o < CO && c < CI) ? Wp[((size_t)o * CI + c) * 9 + dlt] : 0.f;
        uint32_t b0 = __float_as_uint(w);
        uint16_t hi = (uint16_t)(b0 >> 16);
        float r1 = w - __uint_as_float(b0 & 0xFFFF0000u);     // exact
        uint32_t b1 = __float_as_uint(r1);
        uint16_t md = (uint16_t)(b1 >> 16);
        float r2 = r1 - __uint_as_float(b1 & 0xFFFF0000u);    // exact
        uint16_t lo = (uint16_t)(__float_as_uint(r2) >> 16);  // exact (<=8 bits)
        uint32_t pv = (plane == 0) ? hi : ((plane == 1) ? md : lo);
        wb[e >> 1] |= pv << ((e & 1) * 16);
    }
    *(uint4*)(apk + ((size_t)conv * 27 + plane * 9 + dlt) * 512 + lane * 8) =
        make_uint4(wb[0], wb[1], wb[2], wb[3]);
}

// ---------------- conv_scan_mfma: MFMA conv + in-block LIF scan -------------
// Block = 256 thr (4 waves = 4 tau-chunks) x PB positions, all COUT, all T.
// Phase 1: wave wv computes D[32o][32tau] per position (27 mfma_32x32x16),
// stores x=D*scale to LDS [128 rows][130] f32 (stride 130: 2-way-free banks).
// Phase 2: 128 threads scan one row each over t=0..127, write u8 spikes.
// XCD-contiguous vbid swizzle keeps each XCD's sP working set in its L2.
// Layouts as verified in fc_gemm: A k=(lane>>5)*8+e, B col=lane&31,
// D col=lane&31(tau), row o=(r&3)+8*(r>>2)+4*(lane>>5).
template<int COUT, int PB, int H, int W>
__global__ __launch_bounds__(256, 2) void conv_scan_mfma(
    const uint16_t* __restrict__ sP, const uint16_t* __restrict__ apk,
    float scale, uint8_t* __restrict__ sout)
{
    __shared__ float ldsF[128 * 130];            // 66,560 B
    constexpr int HW = H * W;
    constexpr int GP = HW / PB;
    int per = (16 * GP) >> 3;                    // blocks per XCD
    int vbid = (blockIdx.x & 7) * per + (blockIdx.x >> 3);
    int n = vbid / GP, grp = vbid % GP;
    int tid = threadIdx.x;
    int wv = tid >> 6, lane = tid & 63;
    int l31 = lane & 31, lhi = lane >> 5;
    int t0 = wv * 32;

    const uint16_t* ap = apk + (size_t)lane * 8;
    v8s a0[9], a1[9], a2[9];
    #pragma unroll
    for (int d = 0; d < 9; d++) {
        a0[d] = *(const v8s*)(ap + d * 512);
        a1[d] = *(const v8s*)(ap + (9 + d) * 512);
        a2[d] = *(const v8s*)(ap + (18 + d) * 512);
    }

    #pragma unroll
    for (int p = 0; p < PB; p++) {
        int hw = grp * PB + p;
        int hy = hw / W, wx = hw % W;
        v8s bfr[9];
        #pragma unroll
        for (int d = 0; d < 9; d++) {
            int dh = d / 3, dw = d % 3;
            const uint16_t* src = sP
                + ((size_t)((n * (H + 2) + hy + dh) * (W + 2) + wx + dw)) * 2048
                + (t0 + l31) * 16 + lhi * 8;
            bfr[d] = *(const v8s*)src;
        }
        v16f ac0, ac1, ac2;
        #pragma unroll
        for (int e = 0; e < 16; e++) { ac0[e] = 0.f; ac1[e] = 0.f; ac2[e] = 0.f; }
        #pragma unroll
        for (int d = 0; d < 9; d++) {
            ac0 = __builtin_amdgcn_mfma_f32_32x32x16_bf16(a0[d], bfr[d], ac0, 0, 0, 0);
            ac1 = __builtin_amdgcn_mfma_f32_32x32x16_bf16(a1[d], bfr[d], ac1, 0, 0, 0);
            ac2 = __builtin_amdgcn_mfma_f32_32x32x16_bf16(a2[d], bfr[d], ac2, 0, 0, 0);
        }
        constexpr int NR = (COUT == 32) ? 16 : 8;
        #pragma unroll
        for (int r = 0; r < NR; r++) {
            int o = (r & 3) + 8 * (r >> 2) + 4 * lhi;
            ldsF[(o * PB + p) * 130 + t0 + l31] =
                (ac0[r] + ac1[r] + ac2[r]) * scale;
        }
    }
    __syncthreads();
    if (tid < 128) {
        int o = tid / PB, p = tid % PB;
        int hw = grp * PB + p;
        float u = 0.f, v = 0.f;
        uint32_t ob[32];
        const float* xr = &ldsF[tid * 130];
        #pragma unroll
        for (int tb = 0; tb < 32; tb++) {
            float2 xa = *(const float2*)(xr + tb * 4);
            float2 xb = *(const float2*)(xr + tb * 4 + 2);
            float s0, s1, s2, s3;
            neuron_step(xa.x, u, v, s0); neuron_step(xa.y, u, v, s1);
            neuron_step(xb.x, u, v, s2); neuron_step(xb.y, u, v, s3);
            ob[tb] = (uint32_t)s0 | ((uint32_t)s1 << 8) |
                     ((uint32_t)s2 << 16) | ((uint32_t)s3 << 24);
        }
        uint32_t* op = (uint32_t*)(sout + ((size_t)(n * COUT + o) * HW + hw) * 128);
        #pragma unroll
        for (int k = 0; k < 8; k++)
            *(uint4*)&op[k * 4] =
                make_uint4(ob[k*4], ob[k*4+1], ob[k*4+2], ob[k*4+3]);
    }
}

// ---------------- wsplit: fcw[512][3200] -> 3 exact bf16 planes -------------
// w = hi + mid + lo exactly (mantissa truncation 8+8+8 = 24 bits).
__global__ __launch_bounds__(256) void wsplit(
    const float* __restrict__ fw, uint16_t* __restrict__ bs)
{
    int i = blockIdx.x * 256 + threadIdx.x;      // 409,600 threads, 4 elems each
    float4 wv = *(const float4*)(fw + i * 4);
    float w4[4] = {wv.x, wv.y, wv.z, wv.w};
    uint16_t h[4], m[4], l[4];
    #pragma unroll
    for (int j = 0; j < 4; j++) {
        uint32_t b0 = __float_as_uint(w4[j]);
        h[j] = (uint16_t)(b0 >> 16);
        float r1 = w4[j] - __uint_as_float(b0 & 0xFFFF0000u);   // exact
        uint32_t b1 = __float_as_uint(r1);
        m[j] = (uint16_t)(b1 >> 16);
        float r2 = r1 - __uint_as_float(b1 & 0xFFFF0000u);      // exact
        l[j] = (uint16_t)(__float_as_uint(r2) >> 16);           // exact (<=8 bits)
    }
    *(ushort4*)(bs +       0 + i * 4) = make_ushort4(h[0], h[1], h[2], h[3]);
    *(ushort4*)(bs + 1638400 + i * 4) = make_ushort4(m[0], m[1], m[2], m[3]);
    *(ushort4*)(bs + 3276800 + i * 4) = make_ushort4(l[0], l[1], l[2], l[3]);
}

// ---------------- sT: s5 u8 [16][3200][128] -> At bf16 [16][128][3200] ------
// Transpose + delay_shift baked in: At[n][t][c] = s5[n][c][t-1], t=0 -> 0.
__global__ __launch_bounds__(256) void sT_bf16(
    const uint8_t* __restrict__ s5, uint16_t* __restrict__ At)
{
    __shared__ uint8_t tile[64 * 132];           // 64 c-rows x 128 t (+4 pad)
    int bid = blockIdx.x;                        // 800 = 16 n x 50 chunks
    int n = bid / 50;
    int c0 = (bid % 50) * 64;
    int tid = threadIdx.x;
    {
        int row = tid >> 2, q = tid & 3;
        const uint8_t* src = s5 + ((size_t)(n * 3200 + c0 + row)) * T + q * 32;
        *(uint4*)&tile[row * 132 + q * 32]      = *(const uint4*)src;
        *(uint4*)&tile[row * 132 + q * 32 + 16] = *(const uint4*)(src + 16);
    }
    __syncthreads();
    int t = tid >> 1, half = tid & 1;
    uint32_t wb[16];
    if (t == 0) {
        #pragma unroll
        for (int j = 0; j < 16; j++) wb[j] = 0u;
    } else {
        #pragma unroll
        for (int j = 0; j < 16; j++) {
            uint32_t lo = tile[(half * 32 + 2 * j) * 132 + (t - 1)] ? 0x3F80u : 0u;
            uint32_t hi = tile[(half * 32 + 2 * j + 1) * 132 + (t - 1)] ? 0x3F80u : 0u;
            wb[j] = lo | (hi << 16);
        }
    }
    uint16_t* dst = At + ((size_t)(n * 128 + t)) * 3200 + c0 + half * 32;
    #pragma unroll
    for (int k = 0; k < 4; k++)
        *(uint4*)(dst + k * 8) = make_uint4(wb[k*4], wb[k*4+1], wb[k*4+2], wb[k*4+3]);
}

// ---------------- FC GEMM on matrix cores (4 waves, 2x2 split) --------------
// y[n][t][o] = sum_c At[n][t][c] * (hi+mid+lo)[o][c], K-split 10 -> ypart.
// Block: 256 thr (4 waves: wm=t-half, wn=o-half), tile 128t x 128o, BK=64,
// LDS 64KB single-buffered (2 blocks/CU -> 2 waves/SIMD; R4's 128-thr
// version was 1 wave/SIMD and latency-bound at 6.5% occupancy).
// Accumulation order (kc,kf,s) identical to R4 -> bitwise-same output.
#define GLDS16(g, s) __builtin_amdgcn_global_load_lds( \
    (const __attribute__((address_space(1))) uint32_t*)(g), \
    (__attribute__((address_space(3))) uint32_t*)(s), 16, 0, 0)

__global__ __launch_bounds__(256, 2) void fc_gemm_mfma(
    const uint16_t* __restrict__ At,   // [16][128][3200] bf16
    const uint16_t* __restrict__ Bs,   // [3][512][3200] bf16
    float* __restrict__ ypart)         // [10][16][128][512] f32
{
    __shared__ uint8_t lds[65536];     // A [128][64]bf16 @0; B 3x[128][64] @16K
    int bid = blockIdx.x;              // 640 = 10ks x 4ob x 16n (n fastest)
    int n  = bid & 15;
    int ob = (bid >> 4) & 3;
    int ks = bid >> 6;
    int o0 = ob * 128;
    int cbase = ks * 320;

    int tid = threadIdx.x;
    int w4 = tid >> 6;                 // wave 0..3
    int wm = w4 >> 1;                  // t-half
    int wn = w4 & 1;                   // o-half
    int lane = tid & 63;
    int l31 = lane & 31;
    int lhi = lane >> 5;               // k-half within frag
    int rb = lane >> 3;                // staging: row-in-8
    int gsw = (lane & 7) ^ (rb & 7);   // pre-swizzled source granule

    v16f acc[2][2];
    #pragma unroll
    for (int mi = 0; mi < 2; mi++)
        #pragma unroll
        for (int ni = 0; ni < 2; ni++)
            #pragma unroll
            for (int e = 0; e < 16; e++) acc[mi][ni][e] = 0.0f;

    const uint16_t* Abase = At + (size_t)(n * 128) * 3200 + gsw * 8;

    for (int kc = 0; kc < 5; kc++) {
        int c0 = cbase + kc * 64;
        // ---- stage A: 16 x 1KB chunks, chunk cid = i*4 + w4 ----
        #pragma unroll
        for (int i = 0; i < 4; i++) {
            int cid = i * 4 + w4;
            const uint16_t* src = Abase + (size_t)(cid * 8 + rb) * 3200 + c0;
            GLDS16(src, lds + cid * 1024);
        }
        // ---- stage B: 48 x 1KB chunks ----
        #pragma unroll
        for (int j = 0; j < 12; j++) {
            int cid = j * 4 + w4;
            int f0 = cid * 1024;
            int s = f0 >> 14;                    // split plane
            int r = ((f0 & 16383) >> 7) + rb;    // o-local row
            const uint16_t* src = Bs + (size_t)(s * 512 + o0 + r) * 3200
                                     + c0 + gsw * 8;
            GLDS16(src, lds + 16384 + f0);
        }
        __syncthreads();                         // drains vmcnt before barrier
        // ---- compute: 4 kf x (3 splits x 2 ni x 2 mi) MFMA per wave ----
        #pragma unroll
        for (int kf = 0; kf < 4; kf++) {
            int gc = kf * 2 + lhi;
            v8s av[2];
            #pragma unroll
            for (int mi = 0; mi < 2; mi++) {
                int t = wm * 64 + mi * 32 + l31;
                av[mi] = *(const v8s*)(lds + t * 128 + ((gc ^ (t & 7)) << 4));
            }
            #pragma unroll
            for (int s = 0; s < 3; s++) {
                #pragma unroll
                for (int ni = 0; ni < 2; ni++) {
                    int r = wn * 64 + ni * 32 + l31;
                    v8s bv = *(const v8s*)(lds + 16384 + s * 16384 + r * 128
                                           + ((gc ^ (r & 7)) << 4));
                    #pragma unroll
                    for (int mi = 0; mi < 2; mi++)
                        acc[mi][ni] = __builtin_amdgcn_mfma_f32_32x32x16_bf16(
                            av[mi], bv, acc[mi][ni], 0, 0, 0);
                }
            }
        }
        __syncthreads();                         // LDS safe before next stage
    }
    // ---- epilogue: C/D layout col=lane&31, row=(r&3)+8*(r>>2)+4*(lane>>5) --
    float* yp = ypart + (size_t)ks * 1048576 + (size_t)n * 65536;
    #pragma unroll
    for (int mi = 0; mi < 2; mi++)
        #pragma unroll
        for (int ni = 0; ni < 2; ni++) {
            int o = o0 + wn * 64 + ni * 32 + l31;
            #pragma unroll
            for (int r = 0; r < 16; r++) {
                int trow = wm * 64 + mi * 32 + (r & 3) + 8 * (r >> 2) + 4 * lhi;
                yp[trow * 512 + o] = acc[mi][ni][r];
            }
        }
}

// ---------------- FC partial reduce (10 partials, float4) -------------------
__global__ __launch_bounds__(256) void fc_reduce(
    const float4* __restrict__ yp, float4* __restrict__ ys)
{
    int id = blockIdx.x * 256 + threadIdx.x;          // 262,144
    float4 x = yp[id];
    #pragma unroll
    for (int k = 1; k < 10; k++) {
        float4 y = yp[(size_t)k * 262144 + id];
        x.x += y.x; x.y += y.y; x.z += y.z; x.w += y.w;
    }
    ys[id] = x;
}

__global__ __launch_bounds__(64) void fc_scan(
    const float* __restrict__ ysum,   // [16][128][512]
    float* __restrict__ out)          // [16][512][128]
{
    int id = blockIdx.x * 64 + threadIdx.x;           // 8192
    int o = id & 511;
    int n = id >> 9;
    float u = 0.f, v = 0.f;
    float prev = 0.f;                 // final delay_shift
    for (int tb = 0; tb < T / 4; tb++) {
        float b0, b1, b2, b3;
        float x, s;
        x = ysum[(n * T + tb * 4 + 0) * 512 + o]; neuron_step(x, u, v, s); b0 = prev; prev = s;
        x = ysum[(n * T + tb * 4 + 1) * 512 + o]; neuron_step(x, u, v, s); b1 = prev; prev = s;
        x = ysum[(n * T + tb * 4 + 2) * 512 + o]; neuron_step(x, u, v, s); b2 = prev; prev = s;
        x = ysum[(n * T + tb * 4 + 3) * 512 + o]; neuron_step(x, u, v, s); b3 = prev; prev = s;
        *(float4*)&out[((size_t)(n * 512 + o)) * T + tb * 4] = make_float4(b0, b1, b2, b3);
    }
}

// ---------------- launch ----------------------------------------------------
extern "C" void kernel_launch(void* const* d_in, const int* in_sizes, int n_in,
                              void* d_out, int out_size, void* d_ws, size_t ws_size,
                              hipStream_t stream) {
    const float* spike = (const float*)d_in[0];   // [16][2][40][40][128]
    const float* c1w   = (const float*)d_in[1];   // [8][2][3][3]
    const float* c2w   = (const float*)d_in[2];   // [16][8][3][3]
    const float* c3w   = (const float*)d_in[3];   // [32][16][3][3]
    const float* p1w   = (const float*)d_in[4];   // scalar
    const float* p2w   = (const float*)d_in[5];   // scalar
    const float* fcw   = (const float*)d_in[6];   // [512][3200]
    float* out = (float*)d_out;                   // [16][512][128]

    char* ws = (char*)d_ws;
    // Lifetime-ordered map (no fp32 xbuf anymore; max 165,992,448 <
    // 167,116,800 used successfully in earlier rounds):
    uint8_t*  s1    = (uint8_t*)(ws);             // -> 26,214,400
    uint16_t* Bs16  = (uint16_t*)(ws + 26214400); // -> 36,044,800 (alive->fc)
    uint16_t* Apk   = (uint16_t*)(ws + 36044800); // -> 36,100,096 (alive->conv3)
    uint8_t*  s2    = (uint8_t*)(ws + 36100096);  // -> 42,653,696
    uint16_t* s2P   = (uint16_t*)(ws + 42653696); // -> 74,373,120
    uint8_t*  s3    = (uint8_t*)(ws + 74373120);  // -> 87,480,320
    uint8_t*  s4    = (uint8_t*)(ws + 87480320);  // -> 90,757,120
    uint16_t* s4P   = (uint16_t*)(ws + 90757120); // -> 100,194,304
    uint8_t*  s5    = (uint8_t*)(ws + 100194304); // -> 106,747,904
    uint16_t* At16  = (uint16_t*)(ws + 106747904);// -> 119,855,104
    float*    ypart = (float*)(ws + 119855104);   // -> 161,798,144
    float*    ysumb = (float*)(ws + 161798144);   // -> 165,992,448

    conv1_scan<<<3200, 256, 0, stream>>>(spike, c1w, s1);
    wsplit<<<1600, 256, 0, stream>>>(fcw, Bs16);
    apack_w<<<54, 64, 0, stream>>>(c2w, c3w, Apk);

    pool_fused<8, 20, 20><<<200, 256, 0, stream>>>(s1, p1w, s2);
    pad_bf16<8, 20, 20><<<16 * 22 * 22, 256, 0, stream>>>(s2, s2P);
    conv_scan_mfma<16, 8, 20, 20><<<800, 256, 0, stream>>>(s2P, Apk, 100.0f, s3);

    pool_fused<16, 10, 10><<<100, 256, 0, stream>>>(s3, p2w, s4);
    pad_bf16<16, 10, 10><<<16 * 12 * 12, 256, 0, stream>>>(s4, s4P);
    conv_scan_mfma<32, 4, 10, 10><<<400, 256, 0, stream>>>(s4P, Apk + 13824, 100.0f, s5);

    sT_bf16<<<800, 256, 0, stream>>>(s5, At16);
    fc_gemm_mfma<<<640, 256, 0, stream>>>(At16, Bs16, ypart);
    fc_reduce<<<1024, 256, 0, stream>>>((const float4*)ypart, (float4*)ysumb);
    fc_scan<<<128, 64, 0, stream>>>(ysumb, out);
}